// Round 1
// baseline (860.834 us; speedup 1.0000x reference)
//
#include <hip/hip_runtime.h>
#include <cstdint>
#include <cstddef>

// Problem constants
#define B_DIM 16384
#define H_DIM 1024
#define K_DIM 2048   // IN + H (x|h concatenated along K)
#define N_DIM 4096   // 4*H (gate rows, permuted p = 4*h + g)

typedef _Float16 half8 __attribute__((ext_vector_type(8)));
typedef float floatx4 __attribute__((ext_vector_type(4)));

// Async global->LDS, 16B per lane. HW semantics: wave-uniform base + lane*16,
// so the LDS layout must be contiguous in lane order (it is, below).
__device__ __forceinline__ void async_copy16(const void* g, void* l) {
  __builtin_amdgcn_global_load_lds(
      (__attribute__((address_space(1))) void*)g,
      (__attribute__((address_space(3))) void*)l,
      16, 0, 0);
}

// ---------------------------------------------------------------------------
// Pack A = [x | h] as fp16, row-major [B_DIM][K_DIM]. 8 elems/thread.
// ---------------------------------------------------------------------------
__global__ __launch_bounds__(256) void pack_A_kernel(
    const float* __restrict__ x, const float* __restrict__ h,
    _Float16* __restrict__ A) {
  const size_t t = (size_t)blockIdx.x * 256 + threadIdx.x;
  const int row = (int)(t >> 8);          // K_DIM/8 = 256 chunks per row
  const int col = ((int)t & 255) * 8;
  const float* src = (col < H_DIM) ? (x + (size_t)row * H_DIM + col)
                                   : (h + (size_t)row * H_DIM + (col - H_DIM));
  const float4* s4 = (const float4*)src;
  float4 v0 = s4[0];
  float4 v1 = s4[1];
  half8 r = {(_Float16)v0.x, (_Float16)v0.y, (_Float16)v0.z, (_Float16)v0.w,
             (_Float16)v1.x, (_Float16)v1.y, (_Float16)v1.z, (_Float16)v1.w};
  *(half8*)(A + t * 8) = r;
}

// ---------------------------------------------------------------------------
// Pack W = [Wx | Wh] as fp16 with gate-interleaved row permutation:
// permuted row p = 4*h + g  <->  original row j = g*1024 + h.
// A 128-wide N-tile then covers 32 h-indices with all 4 gates -> fusable epilogue.
// ---------------------------------------------------------------------------
__global__ __launch_bounds__(256) void pack_W_kernel(
    const float* __restrict__ Wx, const float* __restrict__ Wh,
    _Float16* __restrict__ Wp) {
  const size_t t = (size_t)blockIdx.x * 256 + threadIdx.x;
  const int p = (int)(t >> 8);
  const int k = ((int)t & 255) * 8;
  const int hidx = p >> 2;
  const int g = p & 3;
  const int j = g * H_DIM + hidx;
  const float* src = (k < H_DIM) ? (Wx + (size_t)j * H_DIM + k)
                                 : (Wh + (size_t)j * H_DIM + (k - H_DIM));
  const float4* s4 = (const float4*)src;
  float4 v0 = s4[0];
  float4 v1 = s4[1];
  half8 r = {(_Float16)v0.x, (_Float16)v0.y, (_Float16)v0.z, (_Float16)v0.w,
             (_Float16)v1.x, (_Float16)v1.y, (_Float16)v1.z, (_Float16)v1.w};
  *(half8*)(Wp + (size_t)p * K_DIM + k) = r;
}

// ---------------------------------------------------------------------------
// Fused GEMM (C = A @ Wp^T) + sLSTM pointwise epilogue.
// m97 structure: 128x128 tile, BK=32, global_load_lds w=16, 4 waves, 4x4 frags.
// ---------------------------------------------------------------------------
__global__ __launch_bounds__(256, 2) void slstm_gemm_fused(
    const _Float16* __restrict__ A,    // [B_DIM][K_DIM]
    const _Float16* __restrict__ Wp,   // [N_DIM][K_DIM], rows permuted p=4h+g
    const float* __restrict__ c_in,
    const float* __restrict__ n_in,
    const float* __restrict__ m_in,
    const float* __restrict__ bias,    // [4096], ORIGINAL order (g*1024+h)
    float* __restrict__ out)           // [4][B_DIM][H_DIM]: h,c,n,m
{
  __shared__ union SM {
    struct { _Float16 As[128 * 32]; _Float16 Bs[128 * 32]; } st;  // 16 KiB
    float cbuf[64 * 132];                                         // 33 KiB
  } sm;

  const int tid  = threadIdx.x;
  const int b0   = blockIdx.x * 128;   // M tile (batch rows)
  const int n0   = blockIdx.y * 128;   // N tile (permuted gate cols)

  const int lane = tid & 63;
  const int wave = tid >> 6;
  const int wm   = wave & 1;   // wave row: rows [wm*64, wm*64+64)
  const int wn   = wave >> 1;  // wave col: cols [wn*64, wn*64+64)
  const int l16  = lane & 15;
  const int quad = lane >> 4;

  // Staging: thread t covers tile elems [t*8, t*8+8) (row t/4, col (t%4)*8),
  // second chunk at +64 rows. Matches global_load_lds lane-order constraint.
  const _Float16* Ag0 = A  + (size_t)(b0 + (tid >> 2)) * K_DIM + (tid & 3) * 8;
  const _Float16* Ag1 = Ag0 + (size_t)64 * K_DIM;
  const _Float16* Wg0 = Wp + (size_t)(n0 + (tid >> 2)) * K_DIM + (tid & 3) * 8;
  const _Float16* Wg1 = Wg0 + (size_t)64 * K_DIM;
  _Float16* lA0 = &sm.st.As[tid * 8];
  _Float16* lA1 = &sm.st.As[(tid + 256) * 8];
  _Float16* lB0 = &sm.st.Bs[tid * 8];
  _Float16* lB1 = &sm.st.Bs[(tid + 256) * 8];

  // Fragment read addresses: A[m=l16][k=quad*8+j], same for B (B^T layout).
  const _Float16* aRd = &sm.st.As[(wm * 64 + l16) * 32 + quad * 8];
  const _Float16* bRd = &sm.st.Bs[(wn * 64 + l16) * 32 + quad * 8];

  floatx4 acc[4][4] = {};

  for (int kt = 0; kt < K_DIM / 32; ++kt) {
    const int ko = kt * 32;
    async_copy16(Ag0 + ko, lA0);
    async_copy16(Ag1 + ko, lA1);
    async_copy16(Wg0 + ko, lB0);
    async_copy16(Wg1 + ko, lB1);
    __syncthreads();   // drains vmcnt (loads landed) + all waves ready

    half8 af[4], bf[4];
#pragma unroll
    for (int i = 0; i < 4; ++i) af[i] = *(const half8*)(aRd + i * 16 * 32);
#pragma unroll
    for (int i = 0; i < 4; ++i) bf[i] = *(const half8*)(bRd + i * 16 * 32);
#pragma unroll
    for (int mi = 0; mi < 4; ++mi)
#pragma unroll
      for (int ni = 0; ni < 4; ++ni)
        acc[mi][ni] = __builtin_amdgcn_mfma_f32_16x16x32_f16(
            af[mi], bf[ni], acc[mi][ni], 0, 0, 0);
    __syncthreads();   // before next stage overwrites LDS
  }

  // -------------------------------------------------------------------------
  // Fused epilogue. C/D layout: col = lane&15, row = quad*4 + reg.
  // Two phases of 64 rows each through a [64][132] f32 LDS buffer; permuted
  // cols mean float4 at col 4*hh holds (i_t, f_t, z_t, o_t) for h = 32*by+hh.
  // -------------------------------------------------------------------------
  const size_t BH = (size_t)B_DIM * H_DIM;
  const int hh = tid & 31;
  const int rb = tid >> 5;
  const int hg = blockIdx.y * 32 + hh;
  const float bi  = bias[hg];
  const float bfv = bias[H_DIM + hg];
  const float bz  = bias[2 * H_DIM + hg];
  const float bo  = bias[3 * H_DIM + hg];

#pragma unroll
  for (int ph = 0; ph < 2; ++ph) {
    if (wm == ph) {
#pragma unroll
      for (int mi = 0; mi < 4; ++mi)
#pragma unroll
        for (int ni = 0; ni < 4; ++ni)
#pragma unroll
          for (int r = 0; r < 4; ++r)
            sm.cbuf[(mi * 16 + quad * 4 + r) * 132 + wn * 64 + ni * 16 + l16] =
                acc[mi][ni][r];
    }
    __syncthreads();

#pragma unroll
    for (int it2 = 0; it2 < 8; ++it2) {
      const int rl = it2 * 8 + rb;             // local row in this 64-row phase
      const int bg = b0 + ph * 64 + rl;        // global batch row
      floatx4 g = *(const floatx4*)&sm.cbuf[rl * 132 + hh * 4];
      const size_t idx = (size_t)bg * H_DIM + hg;

      const float it_ = g.x + bi;
      const float ft_ = g.y + bfv;
      float       zt_ = g.z + bz;
      const float ot_ = g.w + bo;

      const float mo = m_in[idx];
      const float fm = ft_ + mo;
      const float mn = fmaxf(fm, it_);
      const float fg = __expf(fm - mn);        // args <= 0: no overflow
      const float ig = __expf(it_ - mn);
      zt_ = fminf(fmaxf(zt_, -30.0f), 30.0f);
      const float e2 = __expf(2.0f * zt_);
      const float zg = (e2 - 1.0f) / (e2 + 1.0f);   // tanh
      const float og = 1.0f / (1.0f + __expf(-ot_)); // sigmoid
      const float cn = fg * c_in[idx] + ig * zg;
      const float nn = fg * n_in[idx] + ig;
      const float hn = og * (cn / fmaxf(fabsf(nn), 1.0f));

      out[idx]          = hn;
      out[BH + idx]     = cn;
      out[2 * BH + idx] = nn;
      out[3 * BH + idx] = mn;
    }
    __syncthreads();   // before phase 1 overwrites cbuf
  }
}

// ---------------------------------------------------------------------------
extern "C" void kernel_launch(void* const* d_in, const int* in_sizes, int n_in,
                              void* d_out, int out_size, void* d_ws, size_t ws_size,
                              hipStream_t stream) {
  (void)in_sizes; (void)n_in; (void)out_size; (void)ws_size;
  const float* x   = (const float*)d_in[0];
  const float* h   = (const float*)d_in[1];
  const float* c   = (const float*)d_in[2];
  const float* n   = (const float*)d_in[3];
  const float* m   = (const float*)d_in[4];
  const float* Wxw = (const float*)d_in[5];
  const float* Whw = (const float*)d_in[6];
  const float* Whb = (const float*)d_in[7];

  // Workspace layout: A fp16 [16384][2048] (64 MiB) + Wp fp16 [4096][2048] (16 MiB)
  _Float16* A  = (_Float16*)d_ws;
  _Float16* Wp = (_Float16*)((char*)d_ws + (size_t)B_DIM * K_DIM * sizeof(_Float16));

  pack_A_kernel<<<(B_DIM * (K_DIM / 8)) / 256, 256, 0, stream>>>(x, h, A);
  pack_W_kernel<<<(N_DIM * (K_DIM / 8)) / 256, 256, 0, stream>>>(Wxw, Whw, Wp);

  dim3 grid(B_DIM / 128, N_DIM / 128);   // (128, 32)
  slstm_gemm_fused<<<grid, 256, 0, stream>>>(A, Wp, c, n, m, Whb, (float*)d_out);
}